// Round 1
// baseline (361.661 us; speedup 1.0000x reference)
//
#include <hip/hip_runtime.h>

typedef unsigned short u16;
typedef __attribute__((ext_vector_type(8))) short short8;
typedef __attribute__((ext_vector_type(4))) float f32x4;

#define S_LEN 2048
#define HID 2048
#define NQH 32
#define NKV 8
#define HD 64
#define QKVN 3072

__device__ __forceinline__ short f2b(float f){
  unsigned u = __builtin_bit_cast(unsigned, f);
  u += 0x7fffu + ((u >> 16) & 1u);
  return (short)(u >> 16);
}
__device__ __forceinline__ float b2f(u16 v){
  unsigned u = ((unsigned)v) << 16;
  return __builtin_bit_cast(float, u);
}
__device__ __forceinline__ void gll16(const void* g, void* l){
  __builtin_amdgcn_global_load_lds((const __attribute__((address_space(1))) void*)g,
                                   (__attribute__((address_space(3))) void*)l, 16, 0, 0);
}

// ---------------- fp32 -> bf16 convert (8 elems/thread) ----------------
__global__ __launch_bounds__(256) void cvt_bf16(const float* __restrict__ src,
                                                u16* __restrict__ dst, int n8){
  int i = blockIdx.x * 256 + threadIdx.x;
  if (i >= n8) return;
  const float4* s4 = (const float4*)src;
  float4 a = s4[i*2], b = s4[i*2+1];
  short8 o = { f2b(a.x), f2b(a.y), f2b(a.z), f2b(a.w),
               f2b(b.x), f2b(b.y), f2b(b.z), f2b(b.w) };
  *(short8*)(dst + (size_t)i*8) = o;
}

// ---------------- RoPE cos/sin table: [S][32] each ----------------
__global__ __launch_bounds__(256) void rope_table(const int* __restrict__ pos,
                                                  const float* __restrict__ powers,
                                                  float* __restrict__ cost,
                                                  float* __restrict__ sint){
  int i = blockIdx.x * 256 + threadIdx.x;     // S_LEN*32
  int s = i >> 5, d = i & 31;
  float p = (float)pos[s];
  float w = powers[d];
  float sig = 1.0f / (1.0f + expf(-w));
  float inv = powf(10000.0f, -sig);
  float f = p * inv;
  cost[i] = cosf(f);
  sint[i] = sinf(f);
}

// ---------------- GEMM: C[M][Ntot] = A[M][K] * B[*][K]^T  (bf16 in) -----------
// B selected per n-tile from {B0,B1,B2} with boundaries n1,n2 (fused QKV).
template<bool OUTF32>
__global__ __launch_bounds__(256) void gemm_bt(const u16* __restrict__ A,
                                               const u16* __restrict__ B0,
                                               const u16* __restrict__ B1,
                                               const u16* __restrict__ B2,
                                               int n1, int n2,
                                               void* __restrict__ Cout,
                                               int M, int Ntot, int K){
  __shared__ alignas(16) u16 sA[128*64];
  __shared__ alignas(16) u16 sB[128*64];
  const int tid = threadIdx.x, lane = tid & 63, wv = tid >> 6;
  const int wr = wv >> 1, wc = wv & 1;
  const int m0 = blockIdx.y * 128, n0 = blockIdx.x * 128;
  const int lr = lane & 15, lg = lane >> 4;

  const u16* B;
  if (n0 < n1)      B = B0 + (size_t)n0 * K;
  else if (n0 < n2) B = B1 + (size_t)(n0 - n1) * K;
  else              B = B2 + (size_t)(n0 - n2) * K;

  f32x4 acc[4][4] = {};

  for (int k0 = 0; k0 < K; k0 += 64) {
    #pragma unroll
    for (int i = 0; i < 4; ++i) {
      int o = i*4096 + tid*16;            // byte offset in 16KB tile
      int row = o >> 7, colb = o & 127;   // 128 bytes (64 bf16) per row
      gll16(A + (size_t)(m0+row)*K + k0 + (colb >> 1), (char*)sA + i*4096 + wv*1024);
      gll16(B + (size_t)row*K     + k0 + (colb >> 1), (char*)sB + i*4096 + wv*1024);
    }
    __syncthreads();
    #pragma unroll
    for (int kk = 0; kk < 64; kk += 32) {
      short8 af[4], bfr[4];
      #pragma unroll
      for (int m = 0; m < 4; ++m)
        af[m] = *(const short8*)&sA[(wr*64 + m*16 + lr)*64 + kk + lg*8];
      #pragma unroll
      for (int n = 0; n < 4; ++n)
        bfr[n] = *(const short8*)&sB[(wc*64 + n*16 + lr)*64 + kk + lg*8];
      #pragma unroll
      for (int m = 0; m < 4; ++m)
        #pragma unroll
        for (int n = 0; n < 4; ++n)
          acc[m][n] = __builtin_amdgcn_mfma_f32_16x16x32_bf16(af[m], bfr[n], acc[m][n], 0, 0, 0);
    }
    __syncthreads();
  }

  #pragma unroll
  for (int m = 0; m < 4; ++m)
    #pragma unroll
    for (int n = 0; n < 4; ++n)
      #pragma unroll
      for (int r = 0; r < 4; ++r) {
        int row = m0 + wr*64 + m*16 + lg*4 + r;
        int col = n0 + wc*64 + n*16 + lr;
        float v = acc[m][n][r];
        if (OUTF32) ((float*)Cout)[(size_t)row*Ntot + col] = v;
        else        ((u16*)Cout)[(size_t)row*Ntot + col] = (u16)f2b(v);
      }
}

// ---------------- RoPE applied in-place on bf16 qkv [S][3072] ----------------
__global__ __launch_bounds__(256) void rope_apply(u16* __restrict__ qkv,
                                                  const float* __restrict__ cost,
                                                  const float* __restrict__ sint){
  int i = blockIdx.x * 256 + threadIdx.x;   // S*40*4
  int g = i & 3;
  int hd = (i >> 2) % 40;
  int s = i / 160;
  int col = (hd < NQH) ? hd*HD : HID + (hd - NQH)*HD;
  u16* base = qkv + (size_t)s*QKVN + col + g*8;
  short8 lo = *(short8*)base;
  short8 hi = *(short8*)(base + 32);
  short8 olo, ohi;
  #pragma unroll
  for (int j = 0; j < 8; ++j) {
    float c  = cost[s*32 + g*8 + j];
    float sn = sint[s*32 + g*8 + j];
    float x1 = b2f((u16)lo[j]), x2 = b2f((u16)hi[j]);
    olo[j] = f2b(x1*c - x2*sn);
    ohi[j] = f2b(x2*c + x1*sn);
  }
  *(short8*)base = olo;
  *(short8*)(base + 32) = ohi;
}

// ---------------- V transpose: vt[kvh*64+d][s] = qkv[s][2560 + kvh*64 + d] -----
__global__ __launch_bounds__(256) void vt_kernel(const u16* __restrict__ qkv,
                                                 u16* __restrict__ vt){
  int i = blockIdx.x * 256 + threadIdx.x;   // 8*2048*64
  int d = i & 63;
  int s = (i >> 6) & 2047;
  int kvh = i >> 17;
  vt[(size_t)((kvh << 6) | d) * S_LEN + s] =
      qkv[(size_t)s*QKVN + HID + NKV*HD + (kvh << 6) + d];
}

// ---------------- flash attention (causal, GQA) ----------------
// grid: (qtiles=32, heads=32), block 256 (4 waves, each wave = 16 q rows)
__global__ __launch_bounds__(256) void flash_attn(const u16* __restrict__ qkv,
                                                  const u16* __restrict__ vt,
                                                  u16* __restrict__ attn){
  __shared__ alignas(16) u16 p_lds[4][16][32];
  const int tid = threadIdx.x, lane = tid & 63, w = tid >> 6;
  const int h = blockIdx.y;
  const int kvh = h >> 2;
  const int q0 = blockIdx.x * 64 + w * 16;
  const int lr = lane & 15, lg = lane >> 4;

  short8 qf[2];
  #pragma unroll
  for (int kk = 0; kk < 2; ++kk)
    qf[kk] = *(const short8*)&qkv[(size_t)(q0 + lr)*QKVN + h*HD + kk*32 + lg*8];

  f32x4 accO[4] = {};
  float mrow[4] = {-1e30f, -1e30f, -1e30f, -1e30f};
  float lrow[4] = {0.f, 0.f, 0.f, 0.f};

  const int ntiles = (q0 + 15)/32 + 1;
  for (int t = 0; t < ntiles; ++t) {
    const int kt = t*32;
    f32x4 s0 = {0,0,0,0}, s1 = {0,0,0,0};
    #pragma unroll
    for (int kk = 0; kk < 2; ++kk) {
      short8 k0 = *(const short8*)&qkv[(size_t)(kt + lr)*QKVN + HID + kvh*HD + kk*32 + lg*8];
      short8 k1 = *(const short8*)&qkv[(size_t)(kt + 16 + lr)*QKVN + HID + kvh*HD + kk*32 + lg*8];
      s0 = __builtin_amdgcn_mfma_f32_16x16x32_bf16(qf[kk], k0, s0, 0, 0, 0);
      s1 = __builtin_amdgcn_mfma_f32_16x16x32_bf16(qf[kk], k1, s1, 0, 0, 0);
    }
    float alpha[4];
    #pragma unroll
    for (int r = 0; r < 4; ++r) {
      int qr = q0 + lg*4 + r;
      float a = s0[r]*0.125f; if (kt + lr > qr)      a = -1e30f;
      float b = s1[r]*0.125f; if (kt + 16 + lr > qr) b = -1e30f;
      float mx = fmaxf(a, b);
      mx = fmaxf(mx, __shfl_xor(mx, 1));
      mx = fmaxf(mx, __shfl_xor(mx, 2));
      mx = fmaxf(mx, __shfl_xor(mx, 4));
      mx = fmaxf(mx, __shfl_xor(mx, 8));
      float mn = fmaxf(mrow[r], mx);
      alpha[r] = __expf(mrow[r] - mn);
      mrow[r] = mn;
      float p0 = __expf(a - mn), p1 = __expf(b - mn);
      p_lds[w][lg*4 + r][lr]      = (u16)f2b(p0);
      p_lds[w][lg*4 + r][16 + lr] = (u16)f2b(p1);
      float rs = p0 + p1;
      rs += __shfl_xor(rs, 1);
      rs += __shfl_xor(rs, 2);
      rs += __shfl_xor(rs, 4);
      rs += __shfl_xor(rs, 8);
      lrow[r] = lrow[r]*alpha[r] + rs;
    }
    #pragma unroll
    for (int n = 0; n < 4; ++n) {
      f32x4 t4 = accO[n];
      t4[0] *= alpha[0]; t4[1] *= alpha[1]; t4[2] *= alpha[2]; t4[3] *= alpha[3];
      accO[n] = t4;
    }
    short8 pa = *(const short8*)&p_lds[w][lr][lg*8];
    #pragma unroll
    for (int n = 0; n < 4; ++n) {
      short8 vf = *(const short8*)&vt[(size_t)(kvh*64 + n*16 + lr)*S_LEN + kt + lg*8];
      accO[n] = __builtin_amdgcn_mfma_f32_16x16x32_bf16(pa, vf, accO[n], 0, 0, 0);
    }
  }

  #pragma unroll
  for (int n = 0; n < 4; ++n)
    #pragma unroll
    for (int r = 0; r < 4; ++r) {
      int row = q0 + lg*4 + r;
      attn[(size_t)row*HID + h*HD + n*16 + lr] = (u16)f2b(accO[n][r] / lrow[r]);
    }
}

// ---------------- launch ----------------
extern "C" void kernel_launch(void* const* d_in, const int* in_sizes, int n_in,
                              void* d_out, int out_size, void* d_ws, size_t ws_size,
                              hipStream_t stream){
  const float* hs     = (const float*)d_in[0];
  const int*   pos    = (const int*)d_in[1];
  const float* powers = (const float*)d_in[2];
  const float* Wq     = (const float*)d_in[3];
  const float* Wk     = (const float*)d_in[4];
  const float* Wv     = (const float*)d_in[5];
  const float* Wo     = (const float*)d_in[6];
  float* out = (float*)d_out;

  char* ws = (char*)d_ws;
  auto take = [&](size_t bytes){ void* p = ws; ws += (bytes + 255) & ~(size_t)255; return p; };
  u16* hs_b  = (u16*)take((size_t)S_LEN*HID*2);
  u16* wq_b  = (u16*)take((size_t)HID*HID*2);
  u16* wk_b  = (u16*)take((size_t)NKV*HD*HID*2);
  u16* wv_b  = (u16*)take((size_t)NKV*HD*HID*2);
  u16* wo_b  = (u16*)take((size_t)HID*HID*2);
  u16* qkv   = (u16*)take((size_t)S_LEN*QKVN*2);
  u16* vt    = (u16*)take((size_t)NKV*HD*S_LEN*2);
  u16* attnb = (u16*)take((size_t)S_LEN*HID*2);
  float* cost = (float*)take((size_t)S_LEN*32*4);
  float* sint = (float*)take((size_t)S_LEN*32*4);

  // converts
  cvt_bf16<<<2048, 256, 0, stream>>>(hs, hs_b, S_LEN*HID/8);
  cvt_bf16<<<2048, 256, 0, stream>>>(Wq, wq_b, HID*HID/8);
  cvt_bf16<<<512,  256, 0, stream>>>(Wk, wk_b, NKV*HD*HID/8);
  cvt_bf16<<<512,  256, 0, stream>>>(Wv, wv_b, NKV*HD*HID/8);
  cvt_bf16<<<2048, 256, 0, stream>>>(Wo, wo_b, HID*HID/8);
  rope_table<<<S_LEN*32/256, 256, 0, stream>>>(pos, powers, cost, sint);

  // fused QKV projection: N = 2048 (q) + 512 (k) + 512 (v)
  gemm_bt<false><<<dim3(QKVN/128, S_LEN/128), 256, 0, stream>>>(
      hs_b, wq_b, wk_b, wv_b, HID, HID + NKV*HD, qkv, S_LEN, QKVN, HID);

  rope_apply<<<S_LEN*40*4/256, 256, 0, stream>>>(qkv, cost, sint);
  vt_kernel<<<NKV*HD*S_LEN/256, 256, 0, stream>>>(qkv, vt);

  flash_attn<<<dim3(S_LEN/64, NQH), 256, 0, stream>>>(qkv, vt, attnb);

  // output projection
  gemm_bt<true><<<dim3(HID/128, S_LEN/128), 256, 0, stream>>>(
      attnb, wo_b, wo_b, wo_b, 1<<28, 1<<29, out, S_LEN, HID, HID);
}

// Round 3
// 210.120 us; speedup vs baseline: 1.7212x; 1.7212x over previous
//
#include <hip/hip_runtime.h>

typedef unsigned short u16;
typedef __attribute__((ext_vector_type(8))) short short8;
typedef __attribute__((ext_vector_type(4))) short s16x4;
typedef __attribute__((ext_vector_type(4))) float f32x4;
typedef __attribute__((ext_vector_type(2))) unsigned uint2v;

#define S_LEN 2048
#define HID 2048
#define NQH 32
#define NKV 8
#define HD 64
#define QKVN 3072
#define SCLOG2 0.1803368801111204f  /* 0.125 * log2(e) */

__device__ __forceinline__ short f2b(float f){
  unsigned u = __builtin_bit_cast(unsigned, f);
  u += 0x7fffu + ((u >> 16) & 1u);
  return (short)(u >> 16);
}
__device__ __forceinline__ float b2f(u16 v){
  unsigned u = ((unsigned)v) << 16;
  return __builtin_bit_cast(float, u);
}
__device__ __forceinline__ void gll16(const void* g, void* l){
  __builtin_amdgcn_global_load_lds((const __attribute__((address_space(1))) void*)g,
                                   (__attribute__((address_space(3))) void*)l, 16, 0, 0);
}
__device__ __forceinline__ unsigned cvtpk(float a, float b){
  unsigned r;
  asm("v_cvt_pk_bf16_f32 %0, %1, %2" : "=v"(r) : "v"(a), "v"(b));
  return r;
}
__device__ __forceinline__ float ex2(float x){
  float r; asm("v_exp_f32 %0, %1" : "=v"(r) : "v"(x)); return r;
}

// ---------------- fp32 -> bf16 convert (8 elems/thread) ----------------
__global__ __launch_bounds__(256) void cvt_bf16(const float* __restrict__ src,
                                                u16* __restrict__ dst, int n8){
  int i = blockIdx.x * 256 + threadIdx.x;
  if (i >= n8) return;
  const float4* s4 = (const float4*)src;
  float4 a = s4[i*2], b = s4[i*2+1];
  short8 o = { f2b(a.x), f2b(a.y), f2b(a.z), f2b(a.w),
               f2b(b.x), f2b(b.y), f2b(b.z), f2b(b.w) };
  *(short8*)(dst + (size_t)i*8) = o;
}

// ---------------- RoPE cos/sin table: [S][32] each ----------------
__global__ __launch_bounds__(256) void rope_table(const int* __restrict__ pos,
                                                  const float* __restrict__ powers,
                                                  float* __restrict__ cost,
                                                  float* __restrict__ sint){
  int i = blockIdx.x * 256 + threadIdx.x;     // S_LEN*32
  int s = i >> 5, d = i & 31;
  float p = (float)pos[s];
  float w = powers[d];
  float sig = 1.0f / (1.0f + expf(-w));
  float inv = powf(10000.0f, -sig);
  float f = p * inv;
  cost[i] = cosf(f);
  sint[i] = sinf(f);
}

// ---------------- GEMM: C[M][Ntot] = A[M][K] * B[*][K]^T  (bf16 in) -----------
template<bool OUTF32>
__global__ __launch_bounds__(256) void gemm_bt(const u16* __restrict__ A,
                                               const u16* __restrict__ B0,
                                               const u16* __restrict__ B1,
                                               const u16* __restrict__ B2,
                                               int n1, int n2,
                                               void* __restrict__ Cout,
                                               int M, int Ntot, int K){
  __shared__ alignas(16) u16 sA[128*64];
  __shared__ alignas(16) u16 sB[128*64];
  const int tid = threadIdx.x, lane = tid & 63, wv = tid >> 6;
  const int wr = wv >> 1, wc = wv & 1;
  const int m0 = blockIdx.y * 128, n0 = blockIdx.x * 128;
  const int lr = lane & 15, lg = lane >> 4;

  const u16* B;
  if (n0 < n1)      B = B0 + (size_t)n0 * K;
  else if (n0 < n2) B = B1 + (size_t)(n0 - n1) * K;
  else              B = B2 + (size_t)(n0 - n2) * K;

  f32x4 acc[4][4] = {};

  for (int k0 = 0; k0 < K; k0 += 64) {
    #pragma unroll
    for (int i = 0; i < 4; ++i) {
      int o = i*4096 + tid*16;
      int row = o >> 7, colb = o & 127;
      gll16(A + (size_t)(m0+row)*K + k0 + (colb >> 1), (char*)sA + i*4096 + wv*1024);
      gll16(B + (size_t)row*K     + k0 + (colb >> 1), (char*)sB + i*4096 + wv*1024);
    }
    __syncthreads();
    #pragma unroll
    for (int kk = 0; kk < 64; kk += 32) {
      short8 af[4], bfr[4];
      #pragma unroll
      for (int m = 0; m < 4; ++m)
        af[m] = *(const short8*)&sA[(wr*64 + m*16 + lr)*64 + kk + lg*8];
      #pragma unroll
      for (int n = 0; n < 4; ++n)
        bfr[n] = *(const short8*)&sB[(wc*64 + n*16 + lr)*64 + kk + lg*8];
      #pragma unroll
      for (int m = 0; m < 4; ++m)
        #pragma unroll
        for (int n = 0; n < 4; ++n)
          acc[m][n] = __builtin_amdgcn_mfma_f32_16x16x32_bf16(af[m], bfr[n], acc[m][n], 0, 0, 0);
    }
    __syncthreads();
  }

  #pragma unroll
  for (int m = 0; m < 4; ++m)
    #pragma unroll
    for (int n = 0; n < 4; ++n)
      #pragma unroll
      for (int r = 0; r < 4; ++r) {
        int row = m0 + wr*64 + m*16 + lg*4 + r;
        int col = n0 + wc*64 + n*16 + lr;
        float v = acc[m][n][r];
        if (OUTF32) ((float*)Cout)[(size_t)row*Ntot + col] = v;
        else        ((u16*)Cout)[(size_t)row*Ntot + col] = (u16)f2b(v);
      }
}

// ---------------- RoPE applied in-place on bf16 qkv [S][3072] ----------------
__global__ __launch_bounds__(256) void rope_apply(u16* __restrict__ qkv,
                                                  const float* __restrict__ cost,
                                                  const float* __restrict__ sint){
  int i = blockIdx.x * 256 + threadIdx.x;   // S*40*4
  int g = i & 3;
  int hd = (i >> 2) % 40;
  int s = i / 160;
  int col = (hd < NQH) ? hd*HD : HID + (hd - NQH)*HD;
  u16* base = qkv + (size_t)s*QKVN + col + g*8;
  short8 lo = *(short8*)base;
  short8 hi = *(short8*)(base + 32);
  short8 olo, ohi;
  #pragma unroll
  for (int j = 0; j < 8; ++j) {
    float c  = cost[s*32 + g*8 + j];
    float sn = sint[s*32 + g*8 + j];
    float x1 = b2f((u16)lo[j]), x2 = b2f((u16)hi[j]);
    olo[j] = f2b(x1*c - x2*sn);
    ohi[j] = f2b(x2*c + x1*sn);
  }
  *(short8*)base = olo;
  *(short8*)(base + 32) = ohi;
}

// ---------------- V transpose: vt[kvh*64+d][s] ----------------
__global__ __launch_bounds__(256) void vt_kernel(const u16* __restrict__ qkv,
                                                 u16* __restrict__ vt){
  int i = blockIdx.x * 256 + threadIdx.x;   // 8*2048*64
  int d = i & 63;
  int s = (i >> 6) & 2047;
  int kvh = i >> 17;
  vt[(size_t)((kvh << 6) | d) * S_LEN + s] =
      qkv[(size_t)s*QKVN + HID + NKV*HD + (kvh << 6) + d];
}

// ---------------- flash attention (causal, GQA, swapped-operand) ----------------
// grid: (16 chunks, 32 heads); block 256 = 4 waves, each wave owns 32 q rows.
// KV tile = 64. K and V^T staged in XOR-swizzled LDS via global_load_lds.
// mfma(K,Q) -> S^T (q = lane&15): softmax lane-local + 2 shfls.
// mfma(V^T,P) -> O (q = lane&15): rescale/normalize lane-local.
__global__ __launch_bounds__(256) void flash_attn(const u16* __restrict__ qkv,
                                                  const u16* __restrict__ vt,
                                                  u16* __restrict__ attn){
  __shared__ alignas(16) u16 sK[64*64];
  __shared__ alignas(16) u16 sVT[64*64];
  __shared__ alignas(16) u16 sP[4][32*64];
  const int tid = threadIdx.x, lane = tid & 63, w = tid >> 6;
  const int h = blockIdx.y, kvh = h >> 2;
  const int chunk = 15 - blockIdx.x;          // longest blocks launch first
  const int q0w = chunk*128 + w*32;
  const int lr = lane & 15, lg = lane >> 4;
  const int l8 = lane >> 3, b8 = lane & 7;
  const int colOff = (b8 ^ (l8 & 7)) * 8;     // pre-swizzled global source column

  // Q fragments (held in registers for the whole kernel)
  short8 qf[2][2];
  #pragma unroll
  for (int qs = 0; qs < 2; ++qs)
    #pragma unroll
    for (int kk = 0; kk < 2; ++kk)
      qf[qs][kk] = *(const short8*)&qkv[(size_t)(q0w + qs*16 + lr)*QKVN + h*HD + kk*32 + lg*8];

  f32x4 accO[2][4] = {};
  float m_run[2] = {-1e30f, -1e30f};
  float l_run[2] = {0.f, 0.f};

  // staging source pointers (this wave stages rows [16w,16w+16) of each tile)
  const u16* srcK = qkv + (size_t)(16*w + l8)*QKVN + HID + kvh*HD + colOff;
  const u16* srcV = vt + (size_t)(kvh*HD + 16*w + l8)*S_LEN + colOff;
  char* dK = (char*)sK  + w*2048;
  char* dV = (char*)sVT + w*2048;

  const int nt = 2*chunk + 2;
  for (int t = 0; t < nt; ++t) {
    const int kt = t*64;
    gll16(srcK + (size_t)kt*QKVN,       dK);
    gll16(srcK + (size_t)(kt+8)*QKVN,   dK + 1024);
    gll16(srcV + kt,                    dV);
    gll16(srcV + kt + (size_t)8*S_LEN,  dV + 1024);
    __syncthreads();

    if (kt <= q0w + 31) {
      // K fragments (A-operand), swizzled reads: 2-way bank = free
      short8 kf[4][2];
      #pragma unroll
      for (int ks = 0; ks < 4; ++ks)
        #pragma unroll
        for (int kk = 0; kk < 2; ++kk)
          kf[ks][kk] = *(const short8*)((const char*)sK + (ks*16 + lr)*128 + (((kk*4 + lg) ^ (lr & 7))*16));

      // S^T = K @ Q^T : rows k, cols q
      f32x4 sc[2][4];
      #pragma unroll
      for (int qs = 0; qs < 2; ++qs)
        #pragma unroll
        for (int ks = 0; ks < 4; ++ks) {
          f32x4 z = {0.f,0.f,0.f,0.f};
          z = __builtin_amdgcn_mfma_f32_16x16x32_bf16(kf[ks][0], qf[qs][0], z, 0, 0, 0);
          z = __builtin_amdgcn_mfma_f32_16x16x32_bf16(kf[ks][1], qf[qs][1], z, 0, 0, 0);
          sc[qs][ks] = z;
        }

      const bool masked = (kt + 63 > q0w);
      #pragma unroll
      for (int qs = 0; qs < 2; ++qs) {
        const int qg = q0w + qs*16 + lr;
        float mx = -1e30f;
        #pragma unroll
        for (int ks = 0; ks < 4; ++ks)
          #pragma unroll
          for (int r = 0; r < 4; ++r) {
            float s = sc[qs][ks][r] * SCLOG2;
            if (masked && (kt + ks*16 + lg*4 + r > qg)) s = -1e30f;
            sc[qs][ks][r] = s;
            mx = fmaxf(mx, s);
          }
        mx = fmaxf(mx, __shfl_xor(mx, 16));
        mx = fmaxf(mx, __shfl_xor(mx, 32));
        const float mn = fmaxf(m_run[qs], mx);
        const float alpha = ex2(m_run[qs] - mn);
        m_run[qs] = mn;

        float ls = 0.f;
        #pragma unroll
        for (int ks = 0; ks < 4; ++ks) {
          float p0 = ex2(sc[qs][ks][0] - mn);
          float p1 = ex2(sc[qs][ks][1] - mn);
          float p2 = ex2(sc[qs][ks][2] - mn);
          float p3 = ex2(sc[qs][ks][3] - mn);
          ls += (p0 + p1) + (p2 + p3);
          uint2v pk = { cvtpk(p0, p1), cvtpk(p2, p3) };
          // 8B write, XOR-swizzled at 16B-block granularity (uniform banks)
          *(uint2v*)((char*)&sP[w][0] + (qs*16 + lr)*128 +
                     (((ks*2 + (lg >> 1)) ^ (lr & 7))*16) + (lg & 1)*8) = pk;
        }
        ls += __shfl_xor(ls, 16);
        ls += __shfl_xor(ls, 32);
        l_run[qs] = l_run[qs]*alpha + ls;

        #pragma unroll
        for (int d = 0; d < 4; ++d) {
          f32x4 t4 = accO[qs][d];
          t4[0]*=alpha; t4[1]*=alpha; t4[2]*=alpha; t4[3]*=alpha;
          accO[qs][d] = t4;
        }
      }

      // O += V^T @ P^T : rows d, cols q
      #pragma unroll
      for (int c = 0; c < 2; ++c) {
        short8 pf[2];
        #pragma unroll
        for (int qs = 0; qs < 2; ++qs)
          pf[qs] = *(const short8*)((const char*)&sP[w][0] + (qs*16 + lr)*128 + (((c*4 + lg) ^ (lr & 7))*16));
        #pragma unroll
        for (int d = 0; d < 4; ++d) {
          short8 vf = *(const short8*)((const char*)sVT + (d*16 + lr)*128 + (((c*4 + lg) ^ (lr & 7))*16));
          #pragma unroll
          for (int qs = 0; qs < 2; ++qs)
            accO[qs][d] = __builtin_amdgcn_mfma_f32_16x16x32_bf16(vf, pf[qs], accO[qs][d], 0, 0, 0);
        }
      }
    }
    __syncthreads();
  }

  // epilogue: normalize (lane-local l) and store 8B per (qs,d)
  #pragma unroll
  for (int qs = 0; qs < 2; ++qs) {
    const float inv = 1.0f / l_run[qs];
    const int q = q0w + qs*16 + lr;
    #pragma unroll
    for (int d = 0; d < 4; ++d) {
      s16x4 o = { f2b(accO[qs][d][0]*inv), f2b(accO[qs][d][1]*inv),
                  f2b(accO[qs][d][2]*inv), f2b(accO[qs][d][3]*inv) };
      *(s16x4*)&attn[(size_t)q*HID + h*HD + d*16 + lg*4] = o;
    }
  }
}

// ---------------- launch ----------------
extern "C" void kernel_launch(void* const* d_in, const int* in_sizes, int n_in,
                              void* d_out, int out_size, void* d_ws, size_t ws_size,
                              hipStream_t stream){
  const float* hs     = (const float*)d_in[0];
  const int*   pos    = (const int*)d_in[1];
  const float* powers = (const float*)d_in[2];
  const float* Wq     = (const float*)d_in[3];
  const float* Wk     = (const float*)d_in[4];
  const float* Wv     = (const float*)d_in[5];
  const float* Wo     = (const float*)d_in[6];
  float* out = (float*)d_out;

  char* ws = (char*)d_ws;
  auto take = [&](size_t bytes){ void* p = ws; ws += (bytes + 255) & ~(size_t)255; return p; };
  u16* hs_b  = (u16*)take((size_t)S_LEN*HID*2);
  u16* wq_b  = (u16*)take((size_t)HID*HID*2);
  u16* wk_b  = (u16*)take((size_t)NKV*HD*HID*2);
  u16* wv_b  = (u16*)take((size_t)NKV*HD*HID*2);
  u16* wo_b  = (u16*)take((size_t)HID*HID*2);
  u16* qkv   = (u16*)take((size_t)S_LEN*QKVN*2);
  u16* vt    = (u16*)take((size_t)NKV*HD*S_LEN*2);
  u16* attnb = (u16*)take((size_t)S_LEN*HID*2);
  float* cost = (float*)take((size_t)S_LEN*32*4);
  float* sint = (float*)take((size_t)S_LEN*32*4);

  cvt_bf16<<<2048, 256, 0, stream>>>(hs, hs_b, S_LEN*HID/8);
  cvt_bf16<<<2048, 256, 0, stream>>>(Wq, wq_b, HID*HID/8);
  cvt_bf16<<<512,  256, 0, stream>>>(Wk, wk_b, NKV*HD*HID/8);
  cvt_bf16<<<512,  256, 0, stream>>>(Wv, wv_b, NKV*HD*HID/8);
  cvt_bf16<<<2048, 256, 0, stream>>>(Wo, wo_b, HID*HID/8);
  rope_table<<<S_LEN*32/256, 256, 0, stream>>>(pos, powers, cost, sint);

  gemm_bt<false><<<dim3(QKVN/128, S_LEN/128), 256, 0, stream>>>(
      hs_b, wq_b, wk_b, wv_b, HID, HID + NKV*HD, qkv, S_LEN, QKVN, HID);

  rope_apply<<<S_LEN*40*4/256, 256, 0, stream>>>(qkv, cost, sint);
  vt_kernel<<<NKV*HD*S_LEN/256, 256, 0, stream>>>(qkv, vt);

  flash_attn<<<dim3(16, NQH), 256, 0, stream>>>(qkv, vt, attnb);

  gemm_bt<true><<<dim3(HID/128, S_LEN/128), 256, 0, stream>>>(
      attnb, wo_b, wo_b, wo_b, 1<<28, 1<<29, out, S_LEN, HID, HID);
}

// Round 4
// 189.957 us; speedup vs baseline: 1.9039x; 1.1061x over previous
//
#include <hip/hip_runtime.h>

typedef unsigned short u16;
typedef __attribute__((ext_vector_type(8))) short short8;
typedef __attribute__((ext_vector_type(4))) short s16x4;
typedef __attribute__((ext_vector_type(4))) float f32x4;
typedef __attribute__((ext_vector_type(2))) unsigned uint2v;

#define S_LEN 2048
#define HID 2048
#define NQH 32
#define NKV 8
#define HD 64
#define QKVN 3072
#define SCLOG2 0.1803368801111204f  /* 0.125 * log2(e) */

__device__ __forceinline__ short f2b(float f){
  unsigned u = __builtin_bit_cast(unsigned, f);
  u += 0x7fffu + ((u >> 16) & 1u);
  return (short)(u >> 16);
}
__device__ __forceinline__ float b2f(u16 v){
  unsigned u = ((unsigned)v) << 16;
  return __builtin_bit_cast(float, u);
}
__device__ __forceinline__ void gll16(const void* g, void* l){
  __builtin_amdgcn_global_load_lds((const __attribute__((address_space(1))) void*)g,
                                   (__attribute__((address_space(3))) void*)l, 16, 0, 0);
}
__device__ __forceinline__ unsigned cvtpk(float a, float b){
  unsigned r;
  asm("v_cvt_pk_bf16_f32 %0, %1, %2" : "=v"(r) : "v"(a), "v"(b));
  return r;
}
__device__ __forceinline__ float ex2(float x){
  float r; asm("v_exp_f32 %0, %1" : "=v"(r) : "v"(x)); return r;
}

// ---------------- fp32 -> bf16 convert (8 elems/thread) ----------------
__global__ __launch_bounds__(256) void cvt_bf16(const float* __restrict__ src,
                                                u16* __restrict__ dst, int n8){
  int i = blockIdx.x * 256 + threadIdx.x;
  if (i >= n8) return;
  const float4* s4 = (const float4*)src;
  float4 a = s4[i*2], b = s4[i*2+1];
  short8 o = { f2b(a.x), f2b(a.y), f2b(a.z), f2b(a.w),
               f2b(b.x), f2b(b.y), f2b(b.z), f2b(b.w) };
  *(short8*)(dst + (size_t)i*8) = o;
}

// ---------------- RoPE cos/sin table: [S][32] each ----------------
__global__ __launch_bounds__(256) void rope_table(const int* __restrict__ pos,
                                                  const float* __restrict__ powers,
                                                  float* __restrict__ cost,
                                                  float* __restrict__ sint){
  int i = blockIdx.x * 256 + threadIdx.x;     // S_LEN*32
  int s = i >> 5, d = i & 31;
  float p = (float)pos[s];
  float w = powers[d];
  float sig = 1.0f / (1.0f + expf(-w));
  float inv = powf(10000.0f, -sig);
  float f = p * inv;
  cost[i] = cosf(f);
  sint[i] = sinf(f);
}

// ---------------- GEMM: C[M][Ntot] = A[M][K] * B[*][K]^T  (bf16 in) -----------
template<bool OUTF32>
__global__ __launch_bounds__(256) void gemm_bt(const u16* __restrict__ A,
                                               const u16* __restrict__ B0,
                                               const u16* __restrict__ B1,
                                               const u16* __restrict__ B2,
                                               int n1, int n2,
                                               void* __restrict__ Cout,
                                               int M, int Ntot, int K){
  __shared__ alignas(16) u16 sA[128*64];
  __shared__ alignas(16) u16 sB[128*64];
  const int tid = threadIdx.x, lane = tid & 63, wv = tid >> 6;
  const int wr = wv >> 1, wc = wv & 1;
  const int m0 = blockIdx.y * 128, n0 = blockIdx.x * 128;
  const int lr = lane & 15, lg = lane >> 4;

  const u16* B;
  if (n0 < n1)      B = B0 + (size_t)n0 * K;
  else if (n0 < n2) B = B1 + (size_t)(n0 - n1) * K;
  else              B = B2 + (size_t)(n0 - n2) * K;

  f32x4 acc[4][4] = {};

  for (int k0 = 0; k0 < K; k0 += 64) {
    #pragma unroll
    for (int i = 0; i < 4; ++i) {
      int o = i*4096 + tid*16;
      int row = o >> 7, colb = o & 127;
      gll16(A + (size_t)(m0+row)*K + k0 + (colb >> 1), (char*)sA + i*4096 + wv*1024);
      gll16(B + (size_t)row*K     + k0 + (colb >> 1), (char*)sB + i*4096 + wv*1024);
    }
    __syncthreads();
    #pragma unroll
    for (int kk = 0; kk < 64; kk += 32) {
      short8 af[4], bfr[4];
      #pragma unroll
      for (int m = 0; m < 4; ++m)
        af[m] = *(const short8*)&sA[(wr*64 + m*16 + lr)*64 + kk + lg*8];
      #pragma unroll
      for (int n = 0; n < 4; ++n)
        bfr[n] = *(const short8*)&sB[(wc*64 + n*16 + lr)*64 + kk + lg*8];
      #pragma unroll
      for (int m = 0; m < 4; ++m)
        #pragma unroll
        for (int n = 0; n < 4; ++n)
          acc[m][n] = __builtin_amdgcn_mfma_f32_16x16x32_bf16(af[m], bfr[n], acc[m][n], 0, 0, 0);
    }
    __syncthreads();
  }

  #pragma unroll
  for (int m = 0; m < 4; ++m)
    #pragma unroll
    for (int n = 0; n < 4; ++n)
      #pragma unroll
      for (int r = 0; r < 4; ++r) {
        int row = m0 + wr*64 + m*16 + lg*4 + r;
        int col = n0 + wc*64 + n*16 + lr;
        float v = acc[m][n][r];
        if (OUTF32) ((float*)Cout)[(size_t)row*Ntot + col] = v;
        else        ((u16*)Cout)[(size_t)row*Ntot + col] = (u16)f2b(v);
      }
}

// ---------------- RoPE applied in-place on bf16 qkv [S][3072] ----------------
__global__ __launch_bounds__(256) void rope_apply(u16* __restrict__ qkv,
                                                  const float* __restrict__ cost,
                                                  const float* __restrict__ sint){
  int i = blockIdx.x * 256 + threadIdx.x;   // S*40*4
  int g = i & 3;
  int hd = (i >> 2) % 40;
  int s = i / 160;
  int col = (hd < NQH) ? hd*HD : HID + (hd - NQH)*HD;
  u16* base = qkv + (size_t)s*QKVN + col + g*8;
  short8 lo = *(short8*)base;
  short8 hi = *(short8*)(base + 32);
  short8 olo, ohi;
  #pragma unroll
  for (int j = 0; j < 8; ++j) {
    float c  = cost[s*32 + g*8 + j];
    float sn = sint[s*32 + g*8 + j];
    float x1 = b2f((u16)lo[j]), x2 = b2f((u16)hi[j]);
    olo[j] = f2b(x1*c - x2*sn);
    ohi[j] = f2b(x2*c + x1*sn);
  }
  *(short8*)base = olo;
  *(short8*)(base + 32) = ohi;
}

// ---------------- V transpose: vt[kvh*64+d][s] ----------------
__global__ __launch_bounds__(256) void vt_kernel(const u16* __restrict__ qkv,
                                                 u16* __restrict__ vt){
  int i = blockIdx.x * 256 + threadIdx.x;   // 8*2048*64
  int d = i & 63;
  int s = (i >> 6) & 2047;
  int kvh = i >> 17;
  vt[(size_t)((kvh << 6) | d) * S_LEN + s] =
      qkv[(size_t)s*QKVN + HID + NKV*HD + (kvh << 6) + d];
}

// ---------------- flash attention (causal, GQA, swapped-operand, paired) ------
// grid: (8 pairs, 32 heads); block 512 = 8 waves, each wave owns 16 q rows.
// Block processes chunk 15-p then chunk p -> uniform 36 KV-tiles per block.
// K/V^T double-buffered in LDS (global_load_lds, both-sides XOR swizzle),
// counted vmcnt + raw barriers so prefetch stays in flight across barriers.
__global__ __launch_bounds__(512) void flash_attn(const u16* __restrict__ qkv,
                                                  const u16* __restrict__ vt,
                                                  u16* __restrict__ attn){
  __shared__ alignas(16) u16 sK[2][64*64];
  __shared__ alignas(16) u16 sVT[2][64*64];
  __shared__ alignas(16) u16 sP[8][16*64];
  const int tid = threadIdx.x, lane = tid & 63, w = tid >> 6;
  const int h = blockIdx.y, kvh = h >> 2;
  const int pair = blockIdx.x;
  const int lr = lane & 15, lg = lane >> 4;
  const int l8 = lane >> 3, b8 = lane & 7;
  const int colOff = (b8 ^ (l8 & 7)) * 8;     // pre-swizzled global source column

  // wave w stages K rows [8w,8w+8) and V^T rows [8w,8w+8) of each tile
  const u16* srcK = qkv + (size_t)(8*w + l8)*QKVN + HID + kvh*HD + colOff;
  const u16* srcV = vt + (size_t)(kvh*HD + 8*w + l8)*S_LEN + colOff;
  char* dK = (char*)sK  + w*1024;
  char* dV = (char*)sVT + w*1024;
  char* pW = (char*)sP + w*2048;

  for (int ph = 0; ph < 2; ++ph) {
    const int chunk = ph ? pair : 15 - pair;
    const int q0w = chunk*128 + w*16;

    short8 qf0 = *(const short8*)&qkv[(size_t)(q0w + lr)*QKVN + h*HD + lg*8];
    short8 qf1 = *(const short8*)&qkv[(size_t)(q0w + lr)*QKVN + h*HD + 32 + lg*8];

    f32x4 accO[4] = {};
    float m_run = -1e30f, l_run = 0.f;
    const int nt = 2*chunk + 2;

    // prologue: stage tile 0 into buf 0
    gll16(srcK, dK);
    gll16(srcV, dV);

    for (int t = 0; t < nt; ++t) {
      const int kt = t*64;
      const int cur = t & 1;
      if (t + 1 < nt) {
        const int kn = kt + 64;
        gll16(srcK + (size_t)kn*QKVN, dK + (cur^1)*8192);
        gll16(srcV + kn,              dV + (cur^1)*8192);
        asm volatile("s_waitcnt vmcnt(2)" ::: "memory");
      } else {
        asm volatile("s_waitcnt vmcnt(0)" ::: "memory");
      }
      __builtin_amdgcn_s_barrier();

      if (kt <= q0w + 15) {
        const char* bK = (const char*)sK  + cur*8192;
        const char* bV = (const char*)sVT + cur*8192;

        short8 kf[4][2];
        #pragma unroll
        for (int ks = 0; ks < 4; ++ks)
          #pragma unroll
          for (int kk = 0; kk < 2; ++kk)
            kf[ks][kk] = *(const short8*)(bK + (ks*16 + lr)*128 + (((kk*4 + lg) ^ (lr & 7))*16));

        // S^T = K @ Q^T : rows k, cols q (q = lane&15)
        f32x4 sc[4];
        #pragma unroll
        for (int ks = 0; ks < 4; ++ks) {
          f32x4 z = {0.f,0.f,0.f,0.f};
          z = __builtin_amdgcn_mfma_f32_16x16x32_bf16(kf[ks][0], qf0, z, 0, 0, 0);
          z = __builtin_amdgcn_mfma_f32_16x16x32_bf16(kf[ks][1], qf1, z, 0, 0, 0);
          sc[ks] = z;
        }

        const bool masked = (kt + 63 > q0w);
        const int qg = q0w + lr;
        float mx = -1e30f;
        #pragma unroll
        for (int ks = 0; ks < 4; ++ks)
          #pragma unroll
          for (int r = 0; r < 4; ++r) {
            float s = sc[ks][r] * SCLOG2;
            if (masked && (kt + ks*16 + lg*4 + r > qg)) s = -1e30f;
            sc[ks][r] = s;
            mx = fmaxf(mx, s);
          }
        mx = fmaxf(mx, __shfl_xor(mx, 16));
        mx = fmaxf(mx, __shfl_xor(mx, 32));

        float alpha = 1.0f;
        if (!__all(mx <= m_run + 8.0f)) {     // defer-max (bound 2^8)
          const float mn = fmaxf(m_run, mx);
          alpha = ex2(m_run - mn);
          m_run = mn;
          #pragma unroll
          for (int d = 0; d < 4; ++d) {
            f32x4 t4 = accO[d];
            t4[0]*=alpha; t4[1]*=alpha; t4[2]*=alpha; t4[3]*=alpha;
            accO[d] = t4;
          }
        }

        float ls = 0.f;
        #pragma unroll
        for (int ks = 0; ks < 4; ++ks) {
          float p0 = ex2(sc[ks][0] - m_run);
          float p1 = ex2(sc[ks][1] - m_run);
          float p2 = ex2(sc[ks][2] - m_run);
          float p3 = ex2(sc[ks][3] - m_run);
          ls += (p0 + p1) + (p2 + p3);
          uint2v pk = { cvtpk(p0, p1), cvtpk(p2, p3) };
          *(uint2v*)(pW + lr*128 + (((ks*2 + (lg >> 1)) ^ (lr & 7))*16) + (lg & 1)*8) = pk;
        }
        ls += __shfl_xor(ls, 16);
        ls += __shfl_xor(ls, 32);
        l_run = l_run*alpha + ls;

        // O += V^T @ P^T : rows d, cols q
        #pragma unroll
        for (int c = 0; c < 2; ++c) {
          short8 pf = *(const short8*)(pW + lr*128 + (((c*4 + lg) ^ (lr & 7))*16));
          #pragma unroll
          for (int d = 0; d < 4; ++d) {
            short8 vf = *(const short8*)(bV + (d*16 + lr)*128 + (((c*4 + lg) ^ (lr & 7))*16));
            accO[d] = __builtin_amdgcn_mfma_f32_16x16x32_bf16(vf, pf, accO[d], 0, 0, 0);
          }
        }
      }

      asm volatile("s_waitcnt lgkmcnt(0)" ::: "memory");
      __builtin_amdgcn_s_barrier();
    }

    // epilogue: normalize (lane-local l) and store
    const float inv = 1.0f / l_run;
    const int q = q0w + lr;
    #pragma unroll
    for (int d = 0; d < 4; ++d) {
      s16x4 o = { f2b(accO[d][0]*inv), f2b(accO[d][1]*inv),
                  f2b(accO[d][2]*inv), f2b(accO[d][3]*inv) };
      *(s16x4*)&attn[(size_t)q*HID + h*HD + d*16 + lg*4] = o;
    }
  }
}

// ---------------- launch ----------------
extern "C" void kernel_launch(void* const* d_in, const int* in_sizes, int n_in,
                              void* d_out, int out_size, void* d_ws, size_t ws_size,
                              hipStream_t stream){
  const float* hs     = (const float*)d_in[0];
  const int*   pos    = (const int*)d_in[1];
  const float* powers = (const float*)d_in[2];
  const float* Wq     = (const float*)d_in[3];
  const float* Wk     = (const float*)d_in[4];
  const float* Wv     = (const float*)d_in[5];
  const float* Wo     = (const float*)d_in[6];
  float* out = (float*)d_out;

  char* ws = (char*)d_ws;
  auto take = [&](size_t bytes){ void* p = ws; ws += (bytes + 255) & ~(size_t)255; return p; };
  u16* hs_b  = (u16*)take((size_t)S_LEN*HID*2);
  u16* wq_b  = (u16*)take((size_t)HID*HID*2);
  u16* wk_b  = (u16*)take((size_t)NKV*HD*HID*2);
  u16* wv_b  = (u16*)take((size_t)NKV*HD*HID*2);
  u16* wo_b  = (u16*)take((size_t)HID*HID*2);
  u16* qkv   = (u16*)take((size_t)S_LEN*QKVN*2);
  u16* vt    = (u16*)take((size_t)NKV*HD*S_LEN*2);
  u16* attnb = (u16*)take((size_t)S_LEN*HID*2);
  float* cost = (float*)take((size_t)S_LEN*32*4);
  float* sint = (float*)take((size_t)S_LEN*32*4);

  cvt_bf16<<<2048, 256, 0, stream>>>(hs, hs_b, S_LEN*HID/8);
  cvt_bf16<<<2048, 256, 0, stream>>>(Wq, wq_b, HID*HID/8);
  cvt_bf16<<<512,  256, 0, stream>>>(Wk, wk_b, NKV*HD*HID/8);
  cvt_bf16<<<512,  256, 0, stream>>>(Wv, wv_b, NKV*HD*HID/8);
  cvt_bf16<<<2048, 256, 0, stream>>>(Wo, wo_b, HID*HID/8);
  rope_table<<<S_LEN*32/256, 256, 0, stream>>>(pos, powers, cost, sint);

  gemm_bt<false><<<dim3(QKVN/128, S_LEN/128), 256, 0, stream>>>(
      hs_b, wq_b, wk_b, wv_b, HID, HID + NKV*HD, qkv, S_LEN, QKVN, HID);

  rope_apply<<<S_LEN*40*4/256, 256, 0, stream>>>(qkv, cost, sint);
  vt_kernel<<<NKV*HD*S_LEN/256, 256, 0, stream>>>(qkv, vt);

  flash_attn<<<dim3(8, NQH), 512, 0, stream>>>(qkv, vt, attnb);

  gemm_bt<true><<<dim3(HID/128, S_LEN/128), 256, 0, stream>>>(
      attnb, wo_b, wo_b, wo_b, 1<<28, 1<<29, out, S_LEN, HID, HID);
}

// Round 5
// 178.997 us; speedup vs baseline: 2.0205x; 1.0612x over previous
//
#include <hip/hip_runtime.h>

typedef unsigned short u16;
typedef __attribute__((ext_vector_type(8))) short short8;
typedef __attribute__((ext_vector_type(4))) short s16x4;
typedef __attribute__((ext_vector_type(4))) float f32x4;
typedef __attribute__((ext_vector_type(2))) unsigned uint2v;

#define S_LEN 2048
#define HID 2048
#define NQH 32
#define NKV 8
#define HD 64
#define QKVN 3072
#define SCLOG2 0.1803368801111204f  /* 0.125 * log2(e) */

__device__ __forceinline__ short f2b(float f){
  unsigned u = __builtin_bit_cast(unsigned, f);
  u += 0x7fffu + ((u >> 16) & 1u);
  return (short)(u >> 16);
}
__device__ __forceinline__ float b2f(u16 v){
  unsigned u = ((unsigned)v) << 16;
  return __builtin_bit_cast(float, u);
}
__device__ __forceinline__ void gll16(const void* g, void* l){
  __builtin_amdgcn_global_load_lds((const __attribute__((address_space(1))) void*)g,
                                   (__attribute__((address_space(3))) void*)l, 16, 0, 0);
}
__device__ __forceinline__ unsigned cvtpk(float a, float b){
  unsigned r;
  asm("v_cvt_pk_bf16_f32 %0, %1, %2" : "=v"(r) : "v"(a), "v"(b));
  return r;
}
__device__ __forceinline__ float ex2(float x){
  float r; asm("v_exp_f32 %0, %1" : "=v"(r) : "v"(x)); return r;
}

// ---------------- fused fp32 -> bf16 convert for all 5 tensors ----------------
// segments (8-elem units): hs 524288 | Wq 524288 | Wk 131072 | Wv 131072 | Wo 524288
__global__ __launch_bounds__(256) void cvt_all(const float* __restrict__ s0,
                                               const float* __restrict__ s1,
                                               const float* __restrict__ s2,
                                               const float* __restrict__ s3,
                                               const float* __restrict__ s4,
                                               u16* __restrict__ d0, u16* __restrict__ d1,
                                               u16* __restrict__ d2, u16* __restrict__ d3,
                                               u16* __restrict__ d4){
  int i = blockIdx.x * 256 + threadIdx.x;
  const float* s; u16* d; int off;
  if      (i <  524288){ s = s0; d = d0; off = i; }
  else if (i < 1048576){ s = s1; d = d1; off = i -  524288; }
  else if (i < 1179648){ s = s2; d = d2; off = i - 1048576; }
  else if (i < 1310720){ s = s3; d = d3; off = i - 1179648; }
  else                 { s = s4; d = d4; off = i - 1310720; }
  const float4* s4p = (const float4*)s;
  float4 a = s4p[off*2], b = s4p[off*2+1];
  short8 o = { f2b(a.x), f2b(a.y), f2b(a.z), f2b(a.w),
               f2b(b.x), f2b(b.y), f2b(b.z), f2b(b.w) };
  *(short8*)(d + (size_t)off*8) = o;
}

// ---------------- RoPE cos/sin table: [S][32] each ----------------
__global__ __launch_bounds__(256) void rope_table(const int* __restrict__ pos,
                                                  const float* __restrict__ powers,
                                                  float* __restrict__ cost,
                                                  float* __restrict__ sint){
  int i = blockIdx.x * 256 + threadIdx.x;     // S_LEN*32
  int s = i >> 5, d = i & 31;
  float p = (float)pos[s];
  float w = powers[d];
  float sig = 1.0f / (1.0f + expf(-w));
  float inv = powf(10000.0f, -sig);
  float f = p * inv;
  cost[i] = cosf(f);
  sint[i] = sinf(f);
}

// ---------------- GEMM: C[M][Ntot] = A[M][K] * B[*][K]^T  (bf16 in) -----------
// ROPE: apply rotary embedding in epilogue for columns < 2560 (q,k regions).
template<bool OUTF32, bool ROPE>
__global__ __launch_bounds__(256) void gemm_bt(const u16* __restrict__ A,
                                               const u16* __restrict__ B0,
                                               const u16* __restrict__ B1,
                                               const u16* __restrict__ B2,
                                               int n1, int n2,
                                               void* __restrict__ Cout,
                                               int M, int Ntot, int K,
                                               const float* __restrict__ cost,
                                               const float* __restrict__ sint){
  __shared__ alignas(16) u16 sA[128*64];
  __shared__ alignas(16) u16 sB[128*64];
  const int tid = threadIdx.x, lane = tid & 63, wv = tid >> 6;
  const int wr = wv >> 1, wc = wv & 1;
  const int m0 = blockIdx.y * 128, n0 = blockIdx.x * 128;
  const int lr = lane & 15, lg = lane >> 4;

  const u16* B;
  if (n0 < n1)      B = B0 + (size_t)n0 * K;
  else if (n0 < n2) B = B1 + (size_t)(n0 - n1) * K;
  else              B = B2 + (size_t)(n0 - n2) * K;

  f32x4 acc[4][4] = {};

  for (int k0 = 0; k0 < K; k0 += 64) {
    #pragma unroll
    for (int i = 0; i < 4; ++i) {
      int o = i*4096 + tid*16;
      int row = o >> 7, colb = o & 127;
      gll16(A + (size_t)(m0+row)*K + k0 + (colb >> 1), (char*)sA + i*4096 + wv*1024);
      gll16(B + (size_t)row*K     + k0 + (colb >> 1), (char*)sB + i*4096 + wv*1024);
    }
    __syncthreads();
    #pragma unroll
    for (int kk = 0; kk < 64; kk += 32) {
      short8 af[4], bfr[4];
      #pragma unroll
      for (int m = 0; m < 4; ++m)
        af[m] = *(const short8*)&sA[(wr*64 + m*16 + lr)*64 + kk + lg*8];
      #pragma unroll
      for (int n = 0; n < 4; ++n)
        bfr[n] = *(const short8*)&sB[(wc*64 + n*16 + lr)*64 + kk + lg*8];
      #pragma unroll
      for (int m = 0; m < 4; ++m)
        #pragma unroll
        for (int n = 0; n < 4; ++n)
          acc[m][n] = __builtin_amdgcn_mfma_f32_16x16x32_bf16(af[m], bfr[n], acc[m][n], 0, 0, 0);
    }
    __syncthreads();
  }

  if (ROPE && n0 < 2560) {
    // q/k region: cols n0+wc*64 .. +64 form one head; d = n*16+lr, pairs (n, n+2)
    #pragma unroll
    for (int m = 0; m < 4; ++m)
      #pragma unroll
      for (int r = 0; r < 4; ++r) {
        int row = m0 + wr*64 + m*16 + lg*4 + r;
        float c0 = cost[row*32 + lr],      s0 = sint[row*32 + lr];
        float c1 = cost[row*32 + 16 + lr], s1 = sint[row*32 + 16 + lr];
        float x0 = acc[m][0][r], x1 = acc[m][1][r];
        float x2 = acc[m][2][r], x3 = acc[m][3][r];
        float o0 = x0*c0 - x2*s0, o2 = x2*c0 + x0*s0;
        float o1 = x1*c1 - x3*s1, o3 = x3*c1 + x1*s1;
        u16* cp = (u16*)Cout + (size_t)row*Ntot + n0 + wc*64 + lr;
        cp[0]  = (u16)f2b(o0);
        cp[16] = (u16)f2b(o1);
        cp[32] = (u16)f2b(o2);
        cp[48] = (u16)f2b(o3);
      }
  } else {
    #pragma unroll
    for (int m = 0; m < 4; ++m)
      #pragma unroll
      for (int n = 0; n < 4; ++n)
        #pragma unroll
        for (int r = 0; r < 4; ++r) {
          int row = m0 + wr*64 + m*16 + lg*4 + r;
          int col = n0 + wc*64 + n*16 + lr;
          float v = acc[m][n][r];
          if (OUTF32) ((float*)Cout)[(size_t)row*Ntot + col] = v;
          else        ((u16*)Cout)[(size_t)row*Ntot + col] = (u16)f2b(v);
        }
  }
}

// ---------------- V transpose: vt[kvh*64+d][s] ----------------
__global__ __launch_bounds__(256) void vt_kernel(const u16* __restrict__ qkv,
                                                 u16* __restrict__ vt){
  int i = blockIdx.x * 256 + threadIdx.x;   // 8*2048*64
  int d = i & 63;
  int s = (i >> 6) & 2047;
  int kvh = i >> 17;
  vt[(size_t)((kvh << 6) | d) * S_LEN + s] =
      qkv[(size_t)s*QKVN + HID + NKV*HD + (kvh << 6) + d];
}

// ---------------- flash attention (causal, GQA, swapped-operand, split) -------
// grid: (8 pairs, 2 halves, 32 heads) = 1024 blocks; block 256 = 4 waves of
// 16 q rows (64-row half-chunk). Block processes (chunk 15-p, half 1-z) then
// (chunk p, half z) -> uniform 33 KV-tiles per block. K/V^T double-buffered
// LDS (global_load_lds + both-sides XOR swizzle), counted vmcnt.
__global__ __launch_bounds__(256) void flash_attn(const u16* __restrict__ qkv,
                                                  const u16* __restrict__ vt,
                                                  u16* __restrict__ attn){
  __shared__ alignas(16) u16 sK[2][64*64];
  __shared__ alignas(16) u16 sVT[2][64*64];
  __shared__ alignas(16) u16 sP[4][16*64];
  const int tid = threadIdx.x, lane = tid & 63, w = tid >> 6;
  const int h = blockIdx.z, kvh = h >> 2;
  const int p = blockIdx.x, z = blockIdx.y;
  const int lr = lane & 15, lg = lane >> 4;
  const int l8 = lane >> 3, b8 = lane & 7;
  const int colOff = (b8 ^ (l8 & 7)) * 8;     // pre-swizzled global source column

  // wave w stages K rows [16w,16w+16) and V^T rows [16w,16w+16) of each tile
  const u16* srcK = qkv + (size_t)(16*w + l8)*QKVN + HID + kvh*HD + colOff;
  const u16* srcV = vt + (size_t)(kvh*HD + 16*w + l8)*S_LEN + colOff;
  char* dK = (char*)sK  + w*2048;
  char* dV = (char*)sVT + w*2048;
  char* pW = (char*)sP + w*2048;

  for (int ph = 0; ph < 2; ++ph) {
    const int chunk = ph ? p : 15 - p;
    const int half  = ph ? z : 1 - z;
    const int q0w = chunk*128 + half*64 + w*16;

    short8 qf0 = *(const short8*)&qkv[(size_t)(q0w + lr)*QKVN + h*HD + lg*8];
    short8 qf1 = *(const short8*)&qkv[(size_t)(q0w + lr)*QKVN + h*HD + 32 + lg*8];

    f32x4 accO[4] = {};
    float m_run = -1e30f, l_run = 0.f;
    const int nt = 2*chunk + half + 1;

    // prologue: stage tile 0 into buf 0 (4 gll16 per wave)
    gll16(srcK,                        dK);
    gll16(srcK + (size_t)8*QKVN,       dK + 1024);
    gll16(srcV,                        dV);
    gll16(srcV + (size_t)8*S_LEN,      dV + 1024);

    for (int t = 0; t < nt; ++t) {
      const int kt = t*64;
      const int cur = t & 1;
      if (t + 1 < nt) {
        const int kn = kt + 64;
        char* nK = dK + (cur^1)*8192;
        char* nV = dV + (cur^1)*8192;
        gll16(srcK + (size_t)kn*QKVN,        nK);
        gll16(srcK + (size_t)(kn+8)*QKVN,    nK + 1024);
        gll16(srcV + kn,                     nV);
        gll16(srcV + kn + (size_t)8*S_LEN,   nV + 1024);
        asm volatile("s_waitcnt vmcnt(4)" ::: "memory");
      } else {
        asm volatile("s_waitcnt vmcnt(0)" ::: "memory");
      }
      __builtin_amdgcn_s_barrier();

      if (kt <= q0w + 15) {
        const char* bK = (const char*)sK  + cur*8192;
        const char* bV = (const char*)sVT + cur*8192;

        short8 kf[4][2];
        #pragma unroll
        for (int ks = 0; ks < 4; ++ks)
          #pragma unroll
          for (int kk = 0; kk < 2; ++kk)
            kf[ks][kk] = *(const short8*)(bK + (ks*16 + lr)*128 + (((kk*4 + lg) ^ (lr & 7))*16));

        // S^T = K @ Q^T : rows k, cols q (q = lane&15)
        f32x4 sc[4];
        #pragma unroll
        for (int ks = 0; ks < 4; ++ks) {
          f32x4 zz = {0.f,0.f,0.f,0.f};
          zz = __builtin_amdgcn_mfma_f32_16x16x32_bf16(kf[ks][0], qf0, zz, 0, 0, 0);
          zz = __builtin_amdgcn_mfma_f32_16x16x32_bf16(kf[ks][1], qf1, zz, 0, 0, 0);
          sc[ks] = zz;
        }

        const bool masked = (kt + 63 > q0w);
        const int qg = q0w + lr;
        float mx = -1e30f;
        #pragma unroll
        for (int ks = 0; ks < 4; ++ks)
          #pragma unroll
          for (int r = 0; r < 4; ++r) {
            float s = sc[ks][r] * SCLOG2;
            if (masked && (kt + ks*16 + lg*4 + r > qg)) s = -1e30f;
            sc[ks][r] = s;
            mx = fmaxf(mx, s);
          }
        mx = fmaxf(mx, __shfl_xor(mx, 16));
        mx = fmaxf(mx, __shfl_xor(mx, 32));

        float alpha = 1.0f;
        if (!__all(mx <= m_run + 8.0f)) {     // defer-max (bound 2^8)
          const float mn = fmaxf(m_run, mx);
          alpha = ex2(m_run - mn);
          m_run = mn;
          #pragma unroll
          for (int d = 0; d < 4; ++d) {
            f32x4 t4 = accO[d];
            t4[0]*=alpha; t4[1]*=alpha; t4[2]*=alpha; t4[3]*=alpha;
            accO[d] = t4;
          }
        }

        float ls = 0.f;
        #pragma unroll
        for (int ks = 0; ks < 4; ++ks) {
          float p0 = ex2(sc[ks][0] - m_run);
          float p1 = ex2(sc[ks][1] - m_run);
          float p2 = ex2(sc[ks][2] - m_run);
          float p3 = ex2(sc[ks][3] - m_run);
          ls += (p0 + p1) + (p2 + p3);
          uint2v pk = { cvtpk(p0, p1), cvtpk(p2, p3) };
          *(uint2v*)(pW + lr*128 + (((ks*2 + (lg >> 1)) ^ (lr & 7))*16) + (lg & 1)*8) = pk;
        }
        ls += __shfl_xor(ls, 16);
        ls += __shfl_xor(ls, 32);
        l_run = l_run*alpha + ls;

        // O += V^T @ P^T : rows d, cols q
        #pragma unroll
        for (int c = 0; c < 2; ++c) {
          short8 pf = *(const short8*)(pW + lr*128 + (((c*4 + lg) ^ (lr & 7))*16));
          #pragma unroll
          for (int d = 0; d < 4; ++d) {
            short8 vf = *(const short8*)(bV + (d*16 + lr)*128 + (((c*4 + lg) ^ (lr & 7))*16));
            accO[d] = __builtin_amdgcn_mfma_f32_16x16x32_bf16(vf, pf, accO[d], 0, 0, 0);
          }
        }
      }

      asm volatile("s_waitcnt lgkmcnt(0)" ::: "memory");
      __builtin_amdgcn_s_barrier();
    }

    // epilogue: normalize (lane-local l) and store
    const float inv = 1.0f / l_run;
    const int q = q0w + lr;
    #pragma unroll
    for (int d = 0; d < 4; ++d) {
      s16x4 o = { f2b(accO[d][0]*inv), f2b(accO[d][1]*inv),
                  f2b(accO[d][2]*inv), f2b(accO[d][3]*inv) };
      *(s16x4*)&attn[(size_t)q*HID + h*HD + d*16 + lg*4] = o;
    }
  }
}

// ---------------- launch ----------------
extern "C" void kernel_launch(void* const* d_in, const int* in_sizes, int n_in,
                              void* d_out, int out_size, void* d_ws, size_t ws_size,
                              hipStream_t stream){
  const float* hs     = (const float*)d_in[0];
  const int*   pos    = (const int*)d_in[1];
  const float* powers = (const float*)d_in[2];
  const float* Wq     = (const float*)d_in[3];
  const float* Wk     = (const float*)d_in[4];
  const float* Wv     = (const float*)d_in[5];
  const float* Wo     = (const float*)d_in[6];
  float* out = (float*)d_out;

  char* ws = (char*)d_ws;
  auto take = [&](size_t bytes){ void* p = ws; ws += (bytes + 255) & ~(size_t)255; return p; };
  u16* hs_b  = (u16*)take((size_t)S_LEN*HID*2);
  u16* wq_b  = (u16*)take((size_t)HID*HID*2);
  u16* wk_b  = (u16*)take((size_t)NKV*HD*HID*2);
  u16* wv_b  = (u16*)take((size_t)NKV*HD*HID*2);
  u16* wo_b  = (u16*)take((size_t)HID*HID*2);
  u16* qkv   = (u16*)take((size_t)S_LEN*QKVN*2);
  u16* vt    = (u16*)take((size_t)NKV*HD*S_LEN*2);
  u16* attnb = (u16*)take((size_t)S_LEN*HID*2);
  float* cost = (float*)take((size_t)S_LEN*32*4);
  float* sint = (float*)take((size_t)S_LEN*32*4);

  cvt_all<<<7168, 256, 0, stream>>>(hs, Wq, Wk, Wv, Wo,
                                    hs_b, wq_b, wk_b, wv_b, wo_b);
  rope_table<<<S_LEN*32/256, 256, 0, stream>>>(pos, powers, cost, sint);

  // fused QKV projection (+RoPE in epilogue): N = 2048 (q) + 512 (k) + 512 (v)
  gemm_bt<false, true><<<dim3(QKVN/128, S_LEN/128), 256, 0, stream>>>(
      hs_b, wq_b, wk_b, wv_b, HID, HID + NKV*HD, qkv, S_LEN, QKVN, HID, cost, sint);

  vt_kernel<<<NKV*HD*S_LEN/256, 256, 0, stream>>>(qkv, vt);

  flash_attn<<<dim3(8, 2, NQH), 256, 0, stream>>>(qkv, vt, attnb);

  gemm_bt<true, false><<<dim3(HID/128, S_LEN/128), 256, 0, stream>>>(
      attnb, wo_b, wo_b, wo_b, 1<<28, 1<<29, out, S_LEN, HID, HID, nullptr, nullptr);
}